// Round 1
// baseline (353.344 us; speedup 1.0000x reference)
//
#include <hip/hip_runtime.h>
#include <math.h>

typedef unsigned short u16;
typedef unsigned int u32;
typedef __attribute__((ext_vector_type(8))) short short8;   // 8 bf16 (4 VGPR)
typedef __attribute__((ext_vector_type(4))) float f32x4;
typedef __attribute__((ext_vector_type(2))) u32 u32x2;
typedef __attribute__((ext_vector_type(4))) u32 u32x4;
typedef __attribute__((ext_vector_type(4))) u16 u16x4;

typedef __attribute__((address_space(1))) const void gmem_t;
typedef __attribute__((address_space(3))) void lmem_t;

__device__ __forceinline__ u16 f2bf(float f) {
  u32 u = __builtin_bit_cast(u32, f);
  u = u + 0x7fffu + ((u >> 16) & 1u);   // RNE
  return (u16)(u >> 16);
}

__device__ __forceinline__ void g2l16(const void* g, void* l) {
  __builtin_amdgcn_global_load_lds((gmem_t*)g, (lmem_t*)l, 16, 0, 0);
}

// ---------------- weight transpose+convert: f32 [R][C] -> bf16 [C][R] ----------------
__global__ __launch_bounds__(256) void wtrans(const float* __restrict__ in,
                                              u16* __restrict__ out, int R, int C) {
  __shared__ float t[64][65];
  int tid = threadIdx.x;
  int nbx = C >> 6;
  int bx = blockIdx.x % nbx, by = blockIdx.x / nbx;
  int r0 = by << 6, c0 = bx << 6;
  int lr = tid >> 2, lc = (tid & 3) << 4;
  const float* src = in + (size_t)(r0 + lr) * C + c0 + lc;
#pragma unroll
  for (int j = 0; j < 4; ++j) {
    f32x4 v = *(const f32x4*)(src + j * 4);
    t[lr][lc + j * 4 + 0] = v.x; t[lr][lc + j * 4 + 1] = v.y;
    t[lr][lc + j * 4 + 2] = v.z; t[lr][lc + j * 4 + 3] = v.w;
  }
  __syncthreads();
  int oc = tid >> 2, orr = (tid & 3) << 4;
  u16* dst = out + (size_t)(c0 + oc) * R + r0 + orr;
  u32 u[8];
#pragma unroll
  for (int j = 0; j < 8; ++j)
    u[j] = (u32)f2bf(t[orr + 2 * j][oc]) | ((u32)f2bf(t[orr + 2 * j + 1][oc]) << 16);
  u32x4 v0; v0.x = u[0]; v0.y = u[1]; v0.z = u[2]; v0.w = u[3];
  u32x4 v1; v1.x = u[4]; v1.y = u[5]; v1.z = u[6]; v1.w = u[7];
  *(u32x4*)(dst) = v0;
  *(u32x4*)(dst + 8) = v1;
}

// ---------------- layernorm: f32 row[1024] -> bf16 ----------------
__global__ __launch_bounds__(256) void lnorm(const float* __restrict__ in,
                                             const float* __restrict__ gw,
                                             const float* __restrict__ bw,
                                             u16* __restrict__ out) {
  int r = blockIdx.x, tid = threadIdx.x;
  const f32x4 v = *((const f32x4*)(in + (size_t)r * 1024) + tid);
  float s = v.x + v.y + v.z + v.w;
  float ss = v.x * v.x + v.y * v.y + v.z * v.z + v.w * v.w;
#pragma unroll
  for (int o = 32; o >= 1; o >>= 1) { s += __shfl_xor(s, o); ss += __shfl_xor(ss, o); }
  __shared__ float red[8];
  int w = tid >> 6;
  if ((tid & 63) == 0) { red[w] = s; red[4 + w] = ss; }
  __syncthreads();
  s = red[0] + red[1] + red[2] + red[3];
  ss = red[4] + red[5] + red[6] + red[7];
  float mu = s * (1.0f / 1024.0f);
  float var = ss * (1.0f / 1024.0f) - mu * mu;
  float rstd = rsqrtf(var + 1e-5f);
  const f32x4 g4 = *((const f32x4*)gw + tid);
  const f32x4 b4 = *((const f32x4*)bw + tid);
  u16x4 o;
  o.x = f2bf((v.x - mu) * rstd * g4.x + b4.x);
  o.y = f2bf((v.y - mu) * rstd * g4.y + b4.y);
  o.z = f2bf((v.z - mu) * rstd * g4.z + b4.z);
  o.w = f2bf((v.w - mu) * rstd * g4.w + b4.w);
  *((u16x4*)(out + (size_t)r * 1024) + tid) = o;
}

// ---------------- GEMM: C[M,N] = A[M,K](bf16,rm) @ BT[N,K](bf16,rm)^T ----------------
// m97 structure: 128x128 tile, BK=32, 4 waves (2x2), global_load_lds(16B),
// XOR-swizzled LDS via pre-swizzled global source (G21), 16x16x32 bf16 MFMA.
// EPI: 0=QKV scatter (q,k,vT bf16)  1=proj(+bias+resid,f32)  2=fc1(+bias+GELU,bf16)  3=fc2(+bias+resid,f32)
template <int EPI>
__global__ __launch_bounds__(256) void gemm_bt(
    const u16* __restrict__ A, const u16* __restrict__ BT, int M, int N, int K,
    const float* __restrict__ bias, const float* __restrict__ resid,
    float* __restrict__ fout, u16* __restrict__ bout,
    u16* __restrict__ bout2, u16* __restrict__ bout3) {
  __shared__ __align__(16) u16 smA[128 * 32];
  __shared__ __align__(16) u16 smB[128 * 32];
  int tid = threadIdx.x;
  int w = tid >> 6, l = tid & 63, lq = l & 15, g = l >> 4;
  int nbx = N >> 7;
  int t = (int)blockIdx.x;
  int cpx = (int)gridDim.x >> 3;          // all grids are %8==0
  t = (t & 7) * cpx + (t >> 3);           // XCD-aware swizzle
  int by = t / nbx, bx = t - by * nbx;
  long brow = (long)by << 7, bcol = (long)bx << 7;
  int wr = w >> 1, wc = w & 1;

  // staging sources: chunk p=(it*256+tid): row=p>>2, global col-chunk (p&3)^(row&3)
  const u16* aS[2]; const u16* bS[2];
#pragma unroll
  for (int it = 0; it < 2; ++it) {
    int p = it * 256 + tid;
    int row = p >> 2;
    int gc = (p & 3) ^ (row & 3);
    aS[it] = A + (size_t)(brow + row) * K + gc * 8;
    bS[it] = BT + (size_t)(bcol + row) * K + gc * 8;
  }
  f32x4 zero = {0.f, 0.f, 0.f, 0.f};
  f32x4 acc[4][4];
#pragma unroll
  for (int m = 0; m < 4; ++m)
#pragma unroll
    for (int n = 0; n < 4; ++n) acc[m][n] = zero;

  for (int k0 = 0; k0 < K; k0 += 32) {
#pragma unroll
    for (int it = 0; it < 2; ++it) {
      g2l16(aS[it] + k0, &smA[it * 2048 + w * 512]);
      g2l16(bS[it] + k0, &smB[it * 2048 + w * 512]);
    }
    __syncthreads();
    short8 af[4], bfb[4];
#pragma unroll
    for (int m = 0; m < 4; ++m) {
      int r = wr * 64 + m * 16 + lq;
      af[m] = *(const short8*)((const char*)smA + (r * 64 + ((g * 16) ^ ((r & 3) << 4))));
    }
#pragma unroll
    for (int n = 0; n < 4; ++n) {
      int r = wc * 64 + n * 16 + lq;
      bfb[n] = *(const short8*)((const char*)smB + (r * 64 + ((g * 16) ^ ((r & 3) << 4))));
    }
#pragma unroll
    for (int m = 0; m < 4; ++m)
#pragma unroll
      for (int n = 0; n < 4; ++n)
        acc[m][n] = __builtin_amdgcn_mfma_f32_16x16x32_bf16(af[m], bfb[n], acc[m][n], 0, 0, 0);
    __syncthreads();
  }

  // epilogue: c[i] -> row=(l>>4)*4+i, col=l&15 (m89-verified)
  long colbase = bcol + wc * 64;
#pragma unroll
  for (int m = 0; m < 4; ++m) {
#pragma unroll
    for (int n = 0; n < 4; ++n) {
      f32x4 v = acc[m][n];
      long col = colbase + n * 16 + lq;
      long row0 = brow + wr * 64 + m * 16 + g * 4;
      if constexpr (EPI == 0) {
        int part = (int)(bcol >> 10);                 // block-uniform (1024%128==0)
        long colq = col - ((long)part << 10);
        int hh = (int)(colq >> 6), d = (int)(colq & 63);
#pragma unroll
        for (int i = 0; i < 4; ++i) {
          long row = row0 + i;
          long b = row >> 11, nq = row & 2047;
          long bh = b * 16 + hh;
          u16 val = f2bf(v[i]);
          if (part == 0)      bout [(bh * 2048 + nq) * 64 + d] = val;       // Q [bh][n][d]
          else if (part == 1) bout2[(bh * 2048 + nq) * 64 + d] = val;       // K [bh][n][d]
          else                bout3[(bh * 64 + d) * 2048 + nq] = val;       // V^T [bh][d][n]
        }
      } else if constexpr (EPI == 1 || EPI == 3) {
        float bb = bias[col];
#pragma unroll
        for (int i = 0; i < 4; ++i) {
          long idx = (row0 + i) * N + col;
          fout[idx] = resid[idx] + v[i] + bb;
        }
      } else {  // EPI == 2: GELU (exact erf)
        float bb = bias[col];
#pragma unroll
        for (int i = 0; i < 4; ++i) {
          float xg = v[i] + bb;
          float ge = 0.5f * xg * (1.0f + erff(xg * 0.70710678118654752f));
          bout[(row0 + i) * N + col] = f2bf(ge);
        }
      }
    }
  }
}

// ---------------- flash attention: Q[bh][n][64], K[bh][n][64], V^T[bh][64][n] -> O[4096][1024] bf16 --------
__global__ __launch_bounds__(256) void attn_fwd(const u16* __restrict__ qb,
                                                const u16* __restrict__ kb,
                                                const u16* __restrict__ vtb,
                                                u16* __restrict__ ob) {
  __shared__ __align__(16) u16 kl[64 * 64];
  __shared__ __align__(16) u16 vl[64 * 64];
  __shared__ __align__(16) u16 pl[4][16 * 72];   // per-wave P, padded stride 72
  int tid = threadIdx.x;
  int w = tid >> 6, l = tid & 63, lq = l & 15, g = l >> 4;
  int bh = (int)blockIdx.x & 31;
  int qt = (int)blockIdx.x >> 5;

  const u16* qrow = qb + ((size_t)bh * 2048 + qt * 64 + w * 16 + lq) * 64 + g * 8;
  short8 qf0 = *(const short8*)qrow;          // Q[q=lq][8g+j]
  short8 qf1 = *(const short8*)(qrow + 32);   // +32 d-chunk

  const u16* kS[2]; const u16* vS[2];
#pragma unroll
  for (int it = 0; it < 2; ++it) {
    int p = it * 256 + tid;
    int row = p >> 3;
    int gc = (p & 7) ^ (row & 7);               // pre-swizzled source (G21)
    kS[it] = kb + ((size_t)bh * 2048 + row) * 64 + gc * 8;
    vS[it] = vtb + ((size_t)bh * 64 + row) * 2048 + gc * 8;
  }
  float m_run = -1e30f, l_run = 0.0f;
  f32x4 zero = {0.f, 0.f, 0.f, 0.f};
  f32x4 accO[4] = {zero, zero, zero, zero};
  const float sc = 0.125f * 1.44269504088896f;  // scale * log2e

  for (int kt0 = 0; kt0 < 2048; kt0 += 64) {
#pragma unroll
    for (int it = 0; it < 2; ++it) {
      g2l16(kS[it] + (size_t)kt0 * 64, &kl[it * 2048 + w * 512]);
      g2l16(vS[it] + kt0,              &vl[it * 2048 + w * 512]);
    }
    __syncthreads();

    // S^T tiles: mfma(K,Q) -> c[i]: kv=kt*16+4g+i, q=lq
    f32x4 s[4];
#pragma unroll
    for (int kt = 0; kt < 4; ++kt) {
      s[kt] = zero;
#pragma unroll
      for (int c = 0; c < 2; ++c) {
        int r = kt * 16 + lq;
        short8 a = *(const short8*)((const char*)kl +
                    (r * 128 + ((g * 16 + c * 64) ^ ((r & 7) << 4))));
        s[kt] = __builtin_amdgcn_mfma_f32_16x16x32_bf16(a, (c ? qf1 : qf0), s[kt], 0, 0, 0);
      }
    }
    // online softmax (stats per q=lq; reduce across the 4 lane-groups)
    float mt = -1e30f;
#pragma unroll
    for (int kt = 0; kt < 4; ++kt)
#pragma unroll
      for (int i = 0; i < 4; ++i) mt = fmaxf(mt, s[kt][i]);
    mt = fmaxf(mt, __shfl_xor(mt, 16));
    mt = fmaxf(mt, __shfl_xor(mt, 32));
    float m_new = fmaxf(m_run, mt);
    float alpha = exp2f((m_run - m_new) * sc);
    float rsum = 0.0f;
    float ps[4][4];
#pragma unroll
    for (int kt = 0; kt < 4; ++kt)
#pragma unroll
      for (int i = 0; i < 4; ++i) {
        float p = exp2f((s[kt][i] - m_new) * sc);
        ps[kt][i] = p;
        rsum += p;
      }
    rsum += __shfl_xor(rsum, 16);
    rsum += __shfl_xor(rsum, 32);
    l_run = l_run * alpha + rsum;
    m_run = m_new;

    // P -> bf16 -> per-wave LDS (becomes PV A-operand)
    char* plw = (char*)&pl[w][0];
#pragma unroll
    for (int kt = 0; kt < 4; ++kt) {
      u32x2 uu;
      uu.x = (u32)f2bf(ps[kt][0]) | ((u32)f2bf(ps[kt][1]) << 16);
      uu.y = (u32)f2bf(ps[kt][2]) | ((u32)f2bf(ps[kt][3]) << 16);
      *(u32x2*)(plw + lq * 144 + kt * 32 + g * 8) = uu;
    }
    // rescale O (rows q=4g+i) by alpha fetched from lane 4g+i
    float af4[4];
#pragma unroll
    for (int i = 0; i < 4; ++i) af4[i] = __shfl(alpha, g * 4 + i);
#pragma unroll
    for (int dt = 0; dt < 4; ++dt)
#pragma unroll
      for (int i = 0; i < 4; ++i) accO[dt][i] *= af4[i];

    // PV: mfma(P, V) -> c[i]: q=4g+i, d=lq
#pragma unroll
    for (int c = 0; c < 2; ++c) {
      short8 pa = *(const short8*)(plw + lq * 144 + g * 16 + c * 64);
#pragma unroll
      for (int dt = 0; dt < 4; ++dt) {
        int r = dt * 16 + lq;
        short8 b = *(const short8*)((const char*)vl +
                    (r * 128 + ((g * 16 + c * 64) ^ ((r & 7) << 4))));
        accO[dt] = __builtin_amdgcn_mfma_f32_16x16x32_bf16(pa, b, accO[dt], 0, 0, 0);
      }
    }
    __syncthreads();
  }
  float li[4];
#pragma unroll
  for (int i = 0; i < 4; ++i) li[i] = 1.0f / __shfl(l_run, g * 4 + i);
  int b = bh >> 4, h = bh & 15;
#pragma unroll
  for (int dt = 0; dt < 4; ++dt)
#pragma unroll
    for (int i = 0; i < 4; ++i) {
      long q = (long)qt * 64 + w * 16 + g * 4 + i;
      long d = dt * 16 + lq;
      ob[((long)b * 2048 + q) * 1024 + h * 64 + d] = f2bf(accO[dt][i] * li[i]);
    }
}

// ---------------- launch ----------------
extern "C" void kernel_launch(void* const* d_in, const int* in_sizes, int n_in,
                              void* d_out, int out_size, void* d_ws, size_t ws_size,
                              hipStream_t stream) {
  const float* x     = (const float*)d_in[0];
  const float* ln1g  = (const float*)d_in[1];
  const float* ln1b  = (const float*)d_in[2];
  const float* qkvw  = (const float*)d_in[3];
  const float* projw = (const float*)d_in[4];
  const float* projb = (const float*)d_in[5];
  const float* ln2g  = (const float*)d_in[6];
  const float* ln2b  = (const float*)d_in[7];
  const float* fc1w  = (const float*)d_in[8];
  const float* fc1b  = (const float*)d_in[9];
  const float* fc2w  = (const float*)d_in[10];
  const float* fc2b  = (const float*)d_in[11];
  char* ws = (char*)d_ws;
  // ws layout (80 MB peak):
  u16* qkv_wt  = (u16*)(ws + 0);          // 6 MB   [3072][1024]
  u16* proj_wt = (u16*)(ws + 6291456);    // 2 MB   [1024][1024]
  u16* fc1_wt  = (u16*)(ws + 8388608);    // 8 MB   [4096][1024]
  u16* fc2_wt  = (u16*)(ws + 16777216);   // 8 MB   [1024][4096]
  u16* h       = (u16*)(ws + 25165824);   // 8 MB   (LN1 out; reused for LN2 out)
  u16* qbuf    = (u16*)(ws + 33554432);   // 8 MB   [32][2048][64]
  u16* kbuf    = (u16*)(ws + 41943040);   // 8 MB
  u16* vtbuf   = (u16*)(ws + 50331648);   // 8 MB   [32][64][2048]
  u16* aout    = (u16*)(ws + 58720256);   // 8 MB   [4096][1024]
  float* y1    = (float*)(ws + 67108864); // 16 MB  f32 residual stream
  u16* gbuf    = (u16*)(ws + 33554432);   // 32 MB  aliases q/k/vt/aout (dead by then)
  float* outp  = (float*)d_out;

  wtrans<<<768, 256, 0, stream>>>(qkvw, qkv_wt, 1024, 3072);
  wtrans<<<256, 256, 0, stream>>>(projw, proj_wt, 1024, 1024);
  wtrans<<<1024, 256, 0, stream>>>(fc1w, fc1_wt, 1024, 4096);
  wtrans<<<1024, 256, 0, stream>>>(fc2w, fc2_wt, 4096, 1024);

  lnorm<<<4096, 256, 0, stream>>>(x, ln1g, ln1b, h);
  gemm_bt<0><<<768, 256, 0, stream>>>(h, qkv_wt, 4096, 3072, 1024,
                                      nullptr, nullptr, nullptr, qbuf, kbuf, vtbuf);
  attn_fwd<<<1024, 256, 0, stream>>>(qbuf, kbuf, vtbuf, aout);
  gemm_bt<1><<<256, 256, 0, stream>>>(aout, proj_wt, 4096, 1024, 1024,
                                      projb, x, y1, nullptr, nullptr, nullptr);
  lnorm<<<4096, 256, 0, stream>>>(y1, ln2g, ln2b, h);
  gemm_bt<2><<<1024, 256, 0, stream>>>(h, fc1_wt, 4096, 4096, 1024,
                                       fc1b, nullptr, nullptr, gbuf, nullptr, nullptr);
  gemm_bt<3><<<256, 256, 0, stream>>>(gbuf, fc2_wt, 4096, 1024, 4096,
                                      fc2b, y1, outp, nullptr, nullptr, nullptr);
}

// Round 2
// 325.277 us; speedup vs baseline: 1.0863x; 1.0863x over previous
//
#include <hip/hip_runtime.h>
#include <math.h>

typedef unsigned short u16;
typedef unsigned int u32;
typedef __attribute__((ext_vector_type(8))) short short8;   // 8 bf16 (4 VGPR)
typedef __attribute__((ext_vector_type(4))) float f32x4;
typedef __attribute__((ext_vector_type(2))) u32 u32x2;
typedef __attribute__((ext_vector_type(4))) u32 u32x4;
typedef __attribute__((ext_vector_type(4))) u16 u16x4;

typedef __attribute__((address_space(1))) const void gmem_t;
typedef __attribute__((address_space(3))) void lmem_t;

__device__ __forceinline__ u16 f2bf(float f) {
  u32 u = __builtin_bit_cast(u32, f);
  u = u + 0x7fffu + ((u >> 16) & 1u);   // RNE
  return (u16)(u >> 16);
}

__device__ __forceinline__ u32 cvt_pk_bf16(float a, float b) {
  u32 r;
  asm("v_cvt_pk_bf16_f32 %0, %1, %2" : "=v"(r) : "v"(a), "v"(b));
  return r;
}

__device__ __forceinline__ void g2l16(const void* g, void* l) {
  __builtin_amdgcn_global_load_lds((gmem_t*)g, (lmem_t*)l, 16, 0, 0);
}

// ---------------- weight transpose+convert: f32 [R][C] -> bf16 [C][R] ----------------
__global__ __launch_bounds__(256) void wtrans(const float* __restrict__ in,
                                              u16* __restrict__ out, int R, int C) {
  __shared__ float t[64][65];
  int tid = threadIdx.x;
  int nbx = C >> 6;
  int bx = blockIdx.x % nbx, by = blockIdx.x / nbx;
  int r0 = by << 6, c0 = bx << 6;
  int lr = tid >> 2, lc = (tid & 3) << 4;
  const float* src = in + (size_t)(r0 + lr) * C + c0 + lc;
#pragma unroll
  for (int j = 0; j < 4; ++j) {
    f32x4 v = *(const f32x4*)(src + j * 4);
    t[lr][lc + j * 4 + 0] = v.x; t[lr][lc + j * 4 + 1] = v.y;
    t[lr][lc + j * 4 + 2] = v.z; t[lr][lc + j * 4 + 3] = v.w;
  }
  __syncthreads();
  int oc = tid >> 2, orr = (tid & 3) << 4;
  u16* dst = out + (size_t)(c0 + oc) * R + r0 + orr;
  u32 u[8];
#pragma unroll
  for (int j = 0; j < 8; ++j)
    u[j] = (u32)f2bf(t[orr + 2 * j][oc]) | ((u32)f2bf(t[orr + 2 * j + 1][oc]) << 16);
  u32x4 v0; v0.x = u[0]; v0.y = u[1]; v0.z = u[2]; v0.w = u[3];
  u32x4 v1; v1.x = u[4]; v1.y = u[5]; v1.z = u[6]; v1.w = u[7];
  *(u32x4*)(dst) = v0;
  *(u32x4*)(dst + 8) = v1;
}

// ---------------- layernorm: f32 row[1024] -> bf16 ----------------
__global__ __launch_bounds__(256) void lnorm(const float* __restrict__ in,
                                             const float* __restrict__ gw,
                                             const float* __restrict__ bw,
                                             u16* __restrict__ out) {
  int r = blockIdx.x, tid = threadIdx.x;
  const f32x4 v = *((const f32x4*)(in + (size_t)r * 1024) + tid);
  float s = v.x + v.y + v.z + v.w;
  float ss = v.x * v.x + v.y * v.y + v.z * v.z + v.w * v.w;
#pragma unroll
  for (int o = 32; o >= 1; o >>= 1) { s += __shfl_xor(s, o); ss += __shfl_xor(ss, o); }
  __shared__ float red[8];
  int w = tid >> 6;
  if ((tid & 63) == 0) { red[w] = s; red[4 + w] = ss; }
  __syncthreads();
  s = red[0] + red[1] + red[2] + red[3];
  ss = red[4] + red[5] + red[6] + red[7];
  float mu = s * (1.0f / 1024.0f);
  float var = ss * (1.0f / 1024.0f) - mu * mu;
  float rstd = rsqrtf(var + 1e-5f);
  const f32x4 g4 = *((const f32x4*)gw + tid);
  const f32x4 b4 = *((const f32x4*)bw + tid);
  u16x4 o;
  o.x = f2bf((v.x - mu) * rstd * g4.x + b4.x);
  o.y = f2bf((v.y - mu) * rstd * g4.y + b4.y);
  o.z = f2bf((v.z - mu) * rstd * g4.z + b4.z);
  o.w = f2bf((v.w - mu) * rstd * g4.w + b4.w);
  *((u16x4*)(out + (size_t)r * 1024) + tid) = o;
}

// ---------------- GEMM: C[M,N] = A[M,K](bf16,rm) @ BT[N,K](bf16,rm)^T ----------------
// m97 structure, templated tile: BMxBN (multiples of 64), BK=32, 4 waves (2x2),
// global_load_lds(16B), XOR-swizzled LDS via pre-swizzled global source (G21).
// EPI: 0=QKV scatter  1=proj(+bias+resid,f32)  2=fc1(+bias+GELU,bf16)  3=fc2(+bias+resid,f32)
template <int EPI, int BM, int BN>
__global__ __launch_bounds__(256) void gemm_bt(
    const u16* __restrict__ A, const u16* __restrict__ BT, int M, int N, int K,
    const float* __restrict__ bias, const float* __restrict__ resid,
    float* __restrict__ fout, u16* __restrict__ bout,
    u16* __restrict__ bout2, u16* __restrict__ bout3) {
  constexpr int AIT = BM / 64, BIT = BN / 64;   // staging iters (256 thr x 16B = 4KB = 64 rows)
  constexpr int MR = BM / 32, NR = BN / 32;     // per-wave 16x16 frags
  __shared__ __align__(16) u16 smA[BM * 32];
  __shared__ __align__(16) u16 smB[BN * 32];
  int tid = threadIdx.x;
  int w = tid >> 6, l = tid & 63, lq = l & 15, g = l >> 4;
  int nbx = N / BN;
  int t = (int)blockIdx.x;
  int cpx = (int)gridDim.x >> 3;          // all grids are %8==0
  t = (t & 7) * cpx + (t >> 3);           // XCD-aware swizzle
  int by = t / nbx, bx = t - by * nbx;
  long brow = (long)by * BM, bcol = (long)bx * BN;
  int wr = w >> 1, wc = w & 1;

  // staging sources: chunk p=(it*256+tid): row=p>>2, global col-chunk (p&3)^(row&3)
  const u16* aS[AIT]; const u16* bS[BIT];
#pragma unroll
  for (int it = 0; it < AIT; ++it) {
    int p = it * 256 + tid;
    int row = p >> 2;
    int gc = (p & 3) ^ (row & 3);
    aS[it] = A + (size_t)(brow + row) * K + gc * 8;
  }
#pragma unroll
  for (int it = 0; it < BIT; ++it) {
    int p = it * 256 + tid;
    int row = p >> 2;
    int gc = (p & 3) ^ (row & 3);
    bS[it] = BT + (size_t)(bcol + row) * K + gc * 8;
  }
  f32x4 zero = {0.f, 0.f, 0.f, 0.f};
  f32x4 acc[MR][NR];
#pragma unroll
  for (int m = 0; m < MR; ++m)
#pragma unroll
    for (int n = 0; n < NR; ++n) acc[m][n] = zero;

  for (int k0 = 0; k0 < K; k0 += 32) {
#pragma unroll
    for (int it = 0; it < AIT; ++it) g2l16(aS[it] + k0, &smA[it * 2048 + w * 512]);
#pragma unroll
    for (int it = 0; it < BIT; ++it) g2l16(bS[it] + k0, &smB[it * 2048 + w * 512]);
    __syncthreads();
    short8 af[MR], bfb[NR];
#pragma unroll
    for (int m = 0; m < MR; ++m) {
      int r = wr * (BM / 2) + m * 16 + lq;
      af[m] = *(const short8*)((const char*)smA + (r * 64 + ((g * 16) ^ ((r & 3) << 4))));
    }
#pragma unroll
    for (int n = 0; n < NR; ++n) {
      int r = wc * (BN / 2) + n * 16 + lq;
      bfb[n] = *(const short8*)((const char*)smB + (r * 64 + ((g * 16) ^ ((r & 3) << 4))));
    }
#pragma unroll
    for (int m = 0; m < MR; ++m)
#pragma unroll
      for (int n = 0; n < NR; ++n)
        acc[m][n] = __builtin_amdgcn_mfma_f32_16x16x32_bf16(af[m], bfb[n], acc[m][n], 0, 0, 0);
    __syncthreads();
  }

  // epilogue: c[i] -> row=(l>>4)*4+i, col=l&15 (m89-verified)
  long colbase = bcol + wc * (BN / 2);
#pragma unroll
  for (int m = 0; m < MR; ++m) {
#pragma unroll
    for (int n = 0; n < NR; ++n) {
      f32x4 v = acc[m][n];
      long col = colbase + n * 16 + lq;
      long row0 = brow + wr * (BM / 2) + m * 16 + g * 4;
      if constexpr (EPI == 0) {
        int part = (int)(bcol >> 10);                 // block-uniform (1024%128==0)
        long colq = col - ((long)part << 10);
        int hh = (int)(colq >> 6), d = (int)(colq & 63);
#pragma unroll
        for (int i = 0; i < 4; ++i) {
          long row = row0 + i;
          long b = row >> 11, nq = row & 2047;
          long bh = b * 16 + hh;
          u16 val = f2bf(v[i]);
          if (part == 0)      bout [(bh * 2048 + nq) * 64 + d] = val;       // Q [bh][n][d]
          else if (part == 1) bout2[(bh * 2048 + nq) * 64 + d] = val;       // K [bh][n][d]
          else                bout3[(bh * 64 + d) * 2048 + nq] = val;       // V^T [bh][d][n]
        }
      } else if constexpr (EPI == 1 || EPI == 3) {
        float bb = bias[col];
#pragma unroll
        for (int i = 0; i < 4; ++i) {
          long idx = (row0 + i) * N + col;
          fout[idx] = resid[idx] + v[i] + bb;
        }
      } else {  // EPI == 2: GELU (exact erf)
        float bb = bias[col];
#pragma unroll
        for (int i = 0; i < 4; ++i) {
          float xg = v[i] + bb;
          float ge = 0.5f * xg * (1.0f + erff(xg * 0.70710678118654752f));
          bout[(row0 + i) * N + col] = f2bf(ge);
        }
      }
    }
  }
}

// ---------------- flash attention: Q[bh][n][64], K[bh][n][64], V^T[bh][64][n] -> O[4096][1024] bf16
// double-buffered K/V LDS, counted vmcnt(4) + raw barriers (T3/T4-lite),
// cvt_pk P-packing (T12 primitive), defer-max rescale skip (T13).
__global__ __launch_bounds__(256) void attn_fwd(const u16* __restrict__ qb,
                                                const u16* __restrict__ kb,
                                                const u16* __restrict__ vtb,
                                                u16* __restrict__ ob) {
  __shared__ __align__(16) u16 kl[2][64 * 64];
  __shared__ __align__(16) u16 vl[2][64 * 64];
  __shared__ __align__(16) u16 pl[4][16 * 72];   // per-wave P, padded stride 72
  int tid = threadIdx.x;
  int w = tid >> 6, l = tid & 63, lq = l & 15, g = l >> 4;
  int bh = (int)blockIdx.x & 31;
  int qt = (int)blockIdx.x >> 5;

  const u16* qrow = qb + ((size_t)bh * 2048 + qt * 64 + w * 16 + lq) * 64 + g * 8;
  short8 qf0 = *(const short8*)qrow;          // Q[q=lq][8g+j]
  short8 qf1 = *(const short8*)(qrow + 32);   // +32 d-chunk

  const u16* kS[2]; const u16* vS[2];
#pragma unroll
  for (int it = 0; it < 2; ++it) {
    int p = it * 256 + tid;
    int row = p >> 3;
    int gc = (p & 7) ^ (row & 7);               // pre-swizzled source (G21)
    kS[it] = kb + ((size_t)bh * 2048 + row) * 64 + gc * 8;
    vS[it] = vtb + ((size_t)bh * 64 + row) * 2048 + gc * 8;
  }
  auto issue = [&](int buf, int kt0) {
#pragma unroll
    for (int it = 0; it < 2; ++it) {
      g2l16(kS[it] + (size_t)kt0 * 64, &kl[buf][it * 2048 + w * 512]);
      g2l16(vS[it] + kt0,              &vl[buf][it * 2048 + w * 512]);
    }
  };

  float m_run = -1e30f, l_run = 0.0f;
  f32x4 zero = {0.f, 0.f, 0.f, 0.f};
  f32x4 accO[4] = {zero, zero, zero, zero};
  const float sc = 0.125f * 1.44269504088896f;  // scale * log2e

  issue(0, 0);                                   // prologue prefetch
  for (int t = 0; t < 32; ++t) {
    int cur = t & 1;
    issue(cur ^ 1, ((t + 1) & 31) << 6);         // prefetch next (wraps harmlessly at t=31)
    asm volatile("s_waitcnt vmcnt(4)" ::: "memory");  // cur's 4 loads done; next's stay in flight
    __builtin_amdgcn_s_barrier();
    asm volatile("" ::: "memory");               // keep ds_reads below the barrier

    const char* klc = (const char*)&kl[cur][0];
    const char* vlc = (const char*)&vl[cur][0];

    // S^T tiles: mfma(K,Q) -> c[i]: kv=kt*16+4g+i, q=lq
    f32x4 s[4];
#pragma unroll
    for (int kt = 0; kt < 4; ++kt) {
      s[kt] = zero;
#pragma unroll
      for (int c = 0; c < 2; ++c) {
        int r = kt * 16 + lq;
        short8 a = *(const short8*)(klc + (r * 128 + ((g * 16 + c * 64) ^ ((r & 7) << 4))));
        s[kt] = __builtin_amdgcn_mfma_f32_16x16x32_bf16(a, (c ? qf1 : qf0), s[kt], 0, 0, 0);
      }
    }
    // online softmax stats (per q=lq; reduce across the 4 lane-groups)
    float mt = -1e30f;
#pragma unroll
    for (int kt = 0; kt < 4; ++kt)
#pragma unroll
      for (int i = 0; i < 4; ++i) mt = fmaxf(mt, s[kt][i]);
    mt = fmaxf(mt, __shfl_xor(mt, 16));
    mt = fmaxf(mt, __shfl_xor(mt, 32));
    // defer-max (T13): only rescale when the running max actually moved
    if (!__all((mt - m_run) * sc <= 8.0f)) {
      float m_new = fmaxf(m_run, mt);
      float alpha = exp2f((m_run - m_new) * sc);
      float af4[4];
#pragma unroll
      for (int i = 0; i < 4; ++i) af4[i] = __shfl(alpha, g * 4 + i);
#pragma unroll
      for (int dt = 0; dt < 4; ++dt)
#pragma unroll
        for (int i = 0; i < 4; ++i) accO[dt][i] *= af4[i];
      m_run = m_new;
    }
    float mrs = m_run * sc;
    float rsum = 0.0f;
    float ps[4][4];
#pragma unroll
    for (int kt = 0; kt < 4; ++kt)
#pragma unroll
      for (int i = 0; i < 4; ++i) {
        float p = exp2f(s[kt][i] * sc - mrs);
        ps[kt][i] = p;
        rsum += p;
      }
    rsum += __shfl_xor(rsum, 16);
    rsum += __shfl_xor(rsum, 32);
    l_run += rsum;

    // P -> bf16 -> per-wave LDS (becomes PV A-operand)
    char* plw = (char*)&pl[w][0];
#pragma unroll
    for (int kt = 0; kt < 4; ++kt) {
      u32x2 uu;
      uu.x = cvt_pk_bf16(ps[kt][0], ps[kt][1]);
      uu.y = cvt_pk_bf16(ps[kt][2], ps[kt][3]);
      *(u32x2*)(plw + lq * 144 + kt * 32 + g * 8) = uu;
    }

    // PV: mfma(P, V) -> c[i]: q=4g+i, d=lq
#pragma unroll
    for (int c = 0; c < 2; ++c) {
      short8 pa = *(const short8*)(plw + lq * 144 + g * 16 + c * 64);
#pragma unroll
      for (int dt = 0; dt < 4; ++dt) {
        int r = dt * 16 + lq;
        short8 b = *(const short8*)(vlc + (r * 128 + ((g * 16 + c * 64) ^ ((r & 7) << 4))));
        accO[dt] = __builtin_amdgcn_mfma_f32_16x16x32_bf16(pa, b, accO[dt], 0, 0, 0);
      }
    }
    asm volatile("" ::: "memory");               // keep buffer reads above the barrier
    __builtin_amdgcn_s_barrier();
  }
  float li[4];
#pragma unroll
  for (int i = 0; i < 4; ++i) li[i] = 1.0f / __shfl(l_run, g * 4 + i);
  int b = bh >> 4, h = bh & 15;
#pragma unroll
  for (int dt = 0; dt < 4; ++dt)
#pragma unroll
    for (int i = 0; i < 4; ++i) {
      long q = (long)qt * 64 + w * 16 + g * 4 + i;
      long d = dt * 16 + lq;
      ob[((long)b * 2048 + q) * 1024 + h * 64 + d] = f2bf(accO[dt][i] * li[i]);
    }
}

// ---------------- launch ----------------
extern "C" void kernel_launch(void* const* d_in, const int* in_sizes, int n_in,
                              void* d_out, int out_size, void* d_ws, size_t ws_size,
                              hipStream_t stream) {
  const float* x     = (const float*)d_in[0];
  const float* ln1g  = (const float*)d_in[1];
  const float* ln1b  = (const float*)d_in[2];
  const float* qkvw  = (const float*)d_in[3];
  const float* projw = (const float*)d_in[4];
  const float* projb = (const float*)d_in[5];
  const float* ln2g  = (const float*)d_in[6];
  const float* ln2b  = (const float*)d_in[7];
  const float* fc1w  = (const float*)d_in[8];
  const float* fc1b  = (const float*)d_in[9];
  const float* fc2w  = (const float*)d_in[10];
  const float* fc2b  = (const float*)d_in[11];
  char* ws = (char*)d_ws;
  u16* qkv_wt  = (u16*)(ws + 0);          // 6 MB   [3072][1024]
  u16* proj_wt = (u16*)(ws + 6291456);    // 2 MB   [1024][1024]
  u16* fc1_wt  = (u16*)(ws + 8388608);    // 8 MB   [4096][1024]
  u16* fc2_wt  = (u16*)(ws + 16777216);   // 8 MB   [1024][4096]
  u16* h       = (u16*)(ws + 25165824);   // 8 MB   (LN1 out; reused for LN2 out)
  u16* qbuf    = (u16*)(ws + 33554432);   // 8 MB   [32][2048][64]
  u16* kbuf    = (u16*)(ws + 41943040);   // 8 MB
  u16* vtbuf   = (u16*)(ws + 50331648);   // 8 MB   [32][64][2048]
  u16* aout    = (u16*)(ws + 58720256);   // 8 MB   [4096][1024]
  float* y1    = (float*)(ws + 67108864); // 16 MB  f32 residual stream
  u16* gbuf    = (u16*)(ws + 33554432);   // 32 MB  aliases q/k/vt/aout (dead by then)
  float* outp  = (float*)d_out;

  wtrans<<<768, 256, 0, stream>>>(qkvw, qkv_wt, 1024, 3072);
  wtrans<<<256, 256, 0, stream>>>(projw, proj_wt, 1024, 1024);
  wtrans<<<1024, 256, 0, stream>>>(fc1w, fc1_wt, 1024, 4096);
  wtrans<<<1024, 256, 0, stream>>>(fc2w, fc2_wt, 4096, 1024);

  lnorm<<<4096, 256, 0, stream>>>(x, ln1g, ln1b, h);
  gemm_bt<0, 128, 128><<<768, 256, 0, stream>>>(h, qkv_wt, 4096, 3072, 1024,
                                      nullptr, nullptr, nullptr, qbuf, kbuf, vtbuf);
  attn_fwd<<<1024, 256, 0, stream>>>(qbuf, kbuf, vtbuf, aout);
  gemm_bt<1, 64, 128><<<512, 256, 0, stream>>>(aout, proj_wt, 4096, 1024, 1024,
                                      projb, x, y1, nullptr, nullptr, nullptr);
  lnorm<<<4096, 256, 0, stream>>>(y1, ln2g, ln2b, h);
  gemm_bt<2, 128, 128><<<1024, 256, 0, stream>>>(h, fc1_wt, 4096, 4096, 1024,
                                       fc1b, nullptr, nullptr, gbuf, nullptr, nullptr);
  gemm_bt<3, 64, 128><<<512, 256, 0, stream>>>(gbuf, fc2_wt, 4096, 1024, 4096,
                                      fc2b, y1, outp, nullptr, nullptr, nullptr);
}